// Round 10
// baseline (203.866 us; speedup 1.0000x reference)
//
#include <hip/hip_runtime.h>
#include <hip/hip_fp16.h>
#include <math.h>

#define N_NODES 100000
#define N_EDGES 1600000
#define EMBED 64
#define HEADS 4
#define HDIM 16

// Padded CSR: 64 slots per node (degree is Poisson(16); max over 100K nodes < 50)
#define SLOTS 64
// Range-partitioned fill: 8 receiver ranges x 500 edge chunks = 4000 blocks
#define NR 8
#define RANGE 12500            // N_NODES / NR
#define NCHUNK 500
#define CHUNK 3200             // N_EDGES / NCHUNK (divisible by 4)
#define NBLK_FILL (NR * NCHUNK)     // 4000
#define NBLK_PROJ (N_NODES / 16)    // 6250

#define LOG2E 1.44269504f

// f32 DPP rotate-add: sum-reduce + broadcast across each 16-lane head group.
template<int CTRL>
__device__ __forceinline__ float ror_add(float t) {
    int x = __builtin_amdgcn_mov_dpp(__float_as_int(t), CTRL, 0xF, 0xF, true);
    return t + __int_as_float(x);
}
__device__ __forceinline__ float head_reduce(float t) {
    t = ror_add<0x121>(t);   // row_ror:1
    t = ror_add<0x122>(t);   // row_ror:2
    t = ror_add<0x124>(t);   // row_ror:4
    t = ror_add<0x128>(t);   // row_ror:8
    return t;
}

// ---------------- Megakernel: fill (blocks 0..3999) + proj (blocks 4000..10249).
// Roles are independent (disjoint outputs); fusing lets fill's atomic-latency
// waves hide under proj's VALU work instead of serializing the two dispatches.
__global__ __launch_bounds__(256) void proj_fill_kernel(
        const float* __restrict__ x,
        const float* __restrict__ Ws, const float* __restrict__ bs,
        const float* __restrict__ Wr, const float* __restrict__ br,
        const int* __restrict__ senders, const int* __restrict__ receivers,
        unsigned short* __restrict__ sph, unsigned short* __restrict__ rph,
        int* __restrict__ cursor, int* __restrict__ csr) {
    if (blockIdx.x < NBLK_FILL) {
        // ---- fill role: range-partitioned padded-CSR build.
        // csr[r*64 + slot] = sender*128 (byte offset into f16 sph rows).
        int range = blockIdx.x & (NR - 1);   // aligns with round-robin XCD mapping
        int chunk = blockIdx.x >> 3;
        int lo = range * RANGE;
        int hi = lo + RANGE;
        const int4* r4 = (const int4*)(receivers + chunk * CHUNK);
        const int4* s4 = (const int4*)(senders  + chunk * CHUNK);
        const int n4 = CHUNK / 4;   // 800
        for (int i = threadIdx.x; i < n4; i += 256) {
            int4 r = r4[i];
            int4 s = s4[i];
            if (r.x >= lo && r.x < hi) { int sl = atomicAdd(&cursor[r.x], 1); if (sl < SLOTS) csr[(r.x << 6) + sl] = s.x << 7; }
            if (r.y >= lo && r.y < hi) { int sl = atomicAdd(&cursor[r.y], 1); if (sl < SLOTS) csr[(r.y << 6) + sl] = s.y << 7; }
            if (r.z >= lo && r.z < hi) { int sl = atomicAdd(&cursor[r.z], 1); if (sl < SLOTS) csr[(r.z << 6) + sl] = s.z << 7; }
            if (r.w >= lo && r.w < hi) { int sl = atomicAdd(&cursor[r.w], 1); if (sl < SLOTS) csr[(r.w << 6) + sl] = s.w << 7; }
        }
    } else {
        // ---- proj role: LDS-staged register-blocked GEMM, f16 outputs.
        __shared__ float wsT[64 * 68];
        __shared__ float wrT[64 * 68];
        __shared__ float xsh[16 * 68];
        int tid = threadIdx.x;
        for (int i = tid; i < 4096; i += 256) {
            int k = i >> 6, o = i & 63;
            wsT[o * 68 + k] = Ws[i];
            wrT[o * 68 + k] = Wr[i];
        }
        int nb = (blockIdx.x - NBLK_FILL) << 4;
        {
            float4 v = ((const float4*)(x + ((size_t)nb << 6)))[tid];
            int n  = tid >> 4;
            int k4 = tid & 15;
            *(float4*)(xsh + n * 68 + (k4 << 2)) = v;
        }
        __syncthreads();
        int o = tid & 63;
        int w = tid >> 6;
        float bsv = bs[o], brv = br[o];
        float accs[4], accr[4];
#pragma unroll
        for (int p = 0; p < 4; ++p) { accs[p] = bsv; accr[p] = brv; }
        const float4* ws4 = (const float4*)wsT + o * 17;
        const float4* wr4 = (const float4*)wrT + o * 17;
        const float4* xs4 = (const float4*)xsh + (w << 2) * 17;
#pragma unroll
        for (int k4 = 0; k4 < 16; ++k4) {
            float4 a = ws4[k4];
            float4 b = wr4[k4];
#pragma unroll
            for (int p = 0; p < 4; ++p) {
                float4 xv = xs4[p * 17 + k4];    // wave-uniform broadcast
                accs[p] += xv.x * a.x + xv.y * a.y + xv.z * a.z + xv.w * a.w;
                accr[p] += xv.x * b.x + xv.y * b.y + xv.z * b.z + xv.w * b.w;
            }
        }
#pragma unroll
        for (int p = 0; p < 4; ++p) {
            int node = nb + (w << 2) + p;
            sph[(node << 6) + o] = __half_as_ushort(__float2half_rn(accs[p]));
            rph[(node << 6) + o] = __half_as_ushort(__float2half_rn(accr[p]));
        }
    }
}

// ---------------- Fused per-node: logits + softmax + weighted gather.
// One wave per node; lane = output element (h*16+d). f32 compute on f16 tables
// (graceful saturation: z>88 -> w=inf -> rcp=0 -> f=1 -> mish=z exactly).
// All batches masked (validity is wave-uniform -> scalar offset select + one
// cndmask on p); double-buffered so batch k+1's loads overlap batch k compute.
__global__ __launch_bounds__(256) void fused_gather_kernel(
                                    const unsigned short* __restrict__ sph,
                                    const unsigned short* __restrict__ rph,
                                    const int* __restrict__ csr,
                                    const int* __restrict__ cursor,
                                    const float* __restrict__ aw,
                                    const float* __restrict__ ab,
                                    float* __restrict__ out) {
    int wave = (blockIdx.x * blockDim.x + threadIdx.x) >> 6;   // grid covers exactly N_NODES
    int lane = threadIdx.x & 63;
    int deg = cursor[wave];
    deg = (deg > SLOTS) ? SLOTS : deg;
    int myoff = csr[(wave << 6) + lane];      // this lane's slot of the csr row
    const char* base = (const char*)sph + (lane << 1);   // csr holds byte offsets
    float rp  = __half2float(__ushort_as_half(rph[(wave << 6) + lane]));
    float awc = aw[lane & 15];
    float abl = ab[0] * LOG2E;
    float rpl = rp * LOG2E;
    float rpa = rp * awc;
    float l = 0.f, acc = 0.f;
    int nbt = (deg + 7) >> 3;
    unsigned short cur[8], nxt[8];
#define LOAD8(dst, i0)                                                          \
    {                                                                           \
        _Pragma("unroll")                                                       \
        for (int j = 0; j < 8; ++j) {                                           \
            int idx = (i0) + j;                                                 \
            int off = __builtin_amdgcn_readlane(myoff, idx);                    \
            off = (idx < deg) ? off : 0;     /* uniform -> scalar select */     \
            dst[j] = *(const unsigned short*)(base + off);                      \
        }                                                                       \
    }
    if (nbt > 0) LOAD8(cur, 0);
    for (int k = 0; k < nbt; ++k) {
        int i0 = k << 3;
        if (k + 1 < nbt) LOAD8(nxt, i0 + 8);
#pragma unroll
        for (int j = 0; j < 8; ++j) {
            float sp  = __half2float(__ushort_as_half(cur[j]));
            float w   = __builtin_amdgcn_exp2f(fmaf(sp, LOG2E, rpl));
            float u   = w + 1.f;
            float den = fmaf(u, u, 1.f);
            float f   = fmaf(-2.f, __builtin_amdgcn_rcpf(den), 1.f);
            float za  = fmaf(sp, awc, rpa);
            float t   = head_reduce(za * f);
            float p   = __builtin_amdgcn_exp2f(fmaf(t, LOG2E, abl));
            p = (i0 + j < deg) ? p : 0.f;
            l += p;
            acc = fmaf(p, sp, acc);
        }
#pragma unroll
        for (int j = 0; j < 8; ++j) cur[j] = nxt[j];
    }
    out[(wave << 6) + lane] = (deg > 0) ? acc * __builtin_amdgcn_rcpf(l) : 0.f;
#undef LOAD8
}

extern "C" void kernel_launch(void* const* d_in, const int* in_sizes, int n_in,
                              void* d_out, int out_size, void* d_ws, size_t ws_size,
                              hipStream_t stream) {
    const float* x  = (const float*)d_in[0];
    const float* Ws = (const float*)d_in[1];
    const float* bs = (const float*)d_in[2];
    const float* Wr = (const float*)d_in[3];
    const float* br = (const float*)d_in[4];
    const float* aw = (const float*)d_in[5];
    const float* ab = (const float*)d_in[6];
    const int* senders   = (const int*)d_in[7];
    const int* receivers = (const int*)d_in[8];
    float* out = (float*)d_out;

    // Workspace layout (~51.6 MB):
    char* wsp = (char*)d_ws;
    unsigned short* sph = (unsigned short*)wsp;  wsp += (size_t)N_NODES * EMBED * 2;  // 12.8 MB
    unsigned short* rph = (unsigned short*)wsp;  wsp += (size_t)N_NODES * EMBED * 2;  // 12.8 MB
    int* csr      = (int*)wsp;    wsp += (size_t)N_NODES * SLOTS * 4;    // 25.6 MB
    int* cursor   = (int*)wsp;    wsp += (size_t)N_NODES * 4;            // 0.4 MB

    // cursor must start at 0 every call (doubles as the degree array afterwards)
    hipMemsetAsync(cursor, 0, (size_t)N_NODES * 4, stream);

    proj_fill_kernel<<<NBLK_FILL + NBLK_PROJ, 256, 0, stream>>>(
        x, Ws, bs, Wr, br, senders, receivers, sph, rph, cursor, csr);

    int gather_blocks = (N_NODES * 64 + 255) / 256;
    fused_gather_kernel<<<gather_blocks, 256, 0, stream>>>(sph, rph, csr, cursor,
                                                           aw, ab, out);
}

// Round 11
// 186.880 us; speedup vs baseline: 1.0909x; 1.0909x over previous
//
#include <hip/hip_runtime.h>
#include <hip/hip_fp16.h>
#include <math.h>

#define N_NODES 100000
#define N_EDGES 1600000
#define EMBED 64
#define HEADS 4
#define HDIM 16

// Padded CSR: 64 slots per node (degree is Poisson(16); max over 100K nodes < 50)
#define SLOTS 64
// Range-partitioned fill: 8 receiver ranges x 500 edge chunks = 4000 blocks
// (standalone kernel, no LDS -> full occupancy; 16000 waves >> 8192 slots)
#define NR 8
#define RANGE 12500            // N_NODES / NR
#define NCHUNK 500
#define CHUNK 3200             // N_EDGES / NCHUNK (divisible by 4)

#define LOG2E 1.44269504f

// Scalar-tail mish: tanh(softplus(z)) = 1 - 2/((1+e^z)^2 + 1); returns mish(z)*awc.
__device__ __forceinline__ float mish_aw(float z, float awc) {
    float ex  = __expf(fminf(z, 30.f));
    float u   = 1.f + ex;
    float den = fmaf(u, u, 1.f);
    float f   = fmaf(-2.f, __builtin_amdgcn_rcpf(den), 1.f);
    return z * awc * f;
}

// f32 DPP rotate-add: sum-reduce + broadcast across each 16-lane head group.
template<int CTRL>
__device__ __forceinline__ float ror_add(float t) {
    int x = __builtin_amdgcn_mov_dpp(__float_as_int(t), CTRL, 0xF, 0xF, true);
    return t + __int_as_float(x);
}
__device__ __forceinline__ float head_reduce(float t) {
    t = ror_add<0x121>(t);   // row_ror:1
    t = ror_add<0x122>(t);   // row_ror:2
    t = ror_add<0x124>(t);   // row_ror:4
    t = ror_add<0x128>(t);   // row_ror:8
    return t;
}

// Packed-f16 DPP rotate-add: reduces BOTH halves (two edges) at once.
template<int CTRL>
__device__ __forceinline__ __half2 hror_add(__half2 t) {
    int x = __builtin_amdgcn_mov_dpp(__builtin_bit_cast(int, t), CTRL, 0xF, 0xF, true);
    return __hadd2(t, __builtin_bit_cast(__half2, x));
}
__device__ __forceinline__ __half2 head_reduce_h2(__half2 t) {
    t = hror_add<0x121>(t);
    t = hror_add<0x122>(t);
    t = hror_add<0x124>(t);
    t = hror_add<0x128>(t);
    return t;
}

// ---------------- Kernel 1: node projections, LDS-staged register-blocked GEMM.
// Outputs stored as f16 (error budget is bf16-grade): sph/rph, 2 B per element.
__global__ __launch_bounds__(256) void proj_kernel(
        const float* __restrict__ x,
        const float* __restrict__ Ws, const float* __restrict__ bs,
        const float* __restrict__ Wr, const float* __restrict__ br,
        unsigned short* __restrict__ sph, unsigned short* __restrict__ rph) {
    __shared__ float wsT[64 * 68];
    __shared__ float wrT[64 * 68];
    __shared__ float xsh[16 * 68];
    int tid = threadIdx.x;
    for (int i = tid; i < 4096; i += 256) {
        int k = i >> 6, o = i & 63;
        wsT[o * 68 + k] = Ws[i];
        wrT[o * 68 + k] = Wr[i];
    }
    int nb = blockIdx.x << 4;
    {
        float4 v = ((const float4*)(x + ((size_t)nb << 6)))[tid];
        int n  = tid >> 4;
        int k4 = tid & 15;
        *(float4*)(xsh + n * 68 + (k4 << 2)) = v;
    }
    __syncthreads();
    int o = tid & 63;
    int w = tid >> 6;
    float bsv = bs[o], brv = br[o];
    float accs[4], accr[4];
#pragma unroll
    for (int p = 0; p < 4; ++p) { accs[p] = bsv; accr[p] = brv; }
    const float4* ws4 = (const float4*)wsT + o * 17;
    const float4* wr4 = (const float4*)wrT + o * 17;
    const float4* xs4 = (const float4*)xsh + (w << 2) * 17;
#pragma unroll
    for (int k4 = 0; k4 < 16; ++k4) {
        float4 a = ws4[k4];
        float4 b = wr4[k4];
#pragma unroll
        for (int p = 0; p < 4; ++p) {
            float4 xv = xs4[p * 17 + k4];    // wave-uniform broadcast
            accs[p] += xv.x * a.x + xv.y * a.y + xv.z * a.z + xv.w * a.w;
            accr[p] += xv.x * b.x + xv.y * b.y + xv.z * b.z + xv.w * b.w;
        }
    }
#pragma unroll
    for (int p = 0; p < 4; ++p) {
        int node = nb + (w << 2) + p;
        sph[(node << 6) + o] = __half_as_ushort(__float2half_rn(accs[p]));
        rph[(node << 6) + o] = __half_as_ushort(__float2half_rn(accr[p]));
    }
}

// ---------------- Range-partitioned padded-CSR fill (standalone: no LDS, high occ).
// csr[r*64 + slot] = sender*128 (pre-shifted BYTE offset into the f16 sph rows).
__global__ void fill_kernel(const int* __restrict__ senders, const int* __restrict__ receivers,
                            int* __restrict__ cursor, int* __restrict__ csr) {
    int range = blockIdx.x & (NR - 1);   // aligns with round-robin XCD mapping
    int chunk = blockIdx.x >> 3;
    int lo = range * RANGE;
    int hi = lo + RANGE;
    const int4* r4 = (const int4*)(receivers + chunk * CHUNK);
    const int4* s4 = (const int4*)(senders  + chunk * CHUNK);
    const int n4 = CHUNK / 4;   // 800
    for (int i = threadIdx.x; i < n4; i += 256) {
        int4 r = r4[i];
        int4 s = s4[i];
        if (r.x >= lo && r.x < hi) { int sl = atomicAdd(&cursor[r.x], 1); if (sl < SLOTS) csr[(r.x << 6) + sl] = s.x << 7; }
        if (r.y >= lo && r.y < hi) { int sl = atomicAdd(&cursor[r.y], 1); if (sl < SLOTS) csr[(r.y << 6) + sl] = s.y << 7; }
        if (r.z >= lo && r.z < hi) { int sl = atomicAdd(&cursor[r.z], 1); if (sl < SLOTS) csr[(r.z << 6) + sl] = s.z << 7; }
        if (r.w >= lo && r.w < hi) { int sl = atomicAdd(&cursor[r.w], 1); if (sl < SLOTS) csr[(r.w << 6) + sl] = s.w << 7; }
    }
}

// ---------------- Fused per-node: logits + softmax + weighted gather.
// One wave per node; lane = output element (h*16+d). f16 tables (12.8 MB each)
// halve the per-XCD L2-fill replication. Per-lane CSR preload + readlane
// broadcast removes all wave-uniform csr loads from the loop.
// e^(sp+rp) = (2^((sp+rp)*log2e/2))^2 keeps f16 in range; overflow is the
// benign saturation path (w=inf -> rcp=0 -> f=1 -> mish=z).
__global__ __launch_bounds__(256) void fused_gather_kernel(
                                    const unsigned short* __restrict__ sph,
                                    const unsigned short* __restrict__ rph,
                                    const int* __restrict__ csr,
                                    const int* __restrict__ cursor,
                                    const float* __restrict__ aw,
                                    const float* __restrict__ ab,
                                    float* __restrict__ out) {
    int wave = (blockIdx.x * blockDim.x + threadIdx.x) >> 6;   // grid covers exactly N_NODES
    int lane = threadIdx.x & 63;
    int deg = cursor[wave];
    deg = (deg > SLOTS) ? SLOTS : deg;
    int myoff = csr[(wave << 6) + lane];      // this lane's slot of the csr row
    const char* splb = (const char*)sph + (lane << 1);   // csr holds byte offsets
    float rp  = __half2float(__ushort_as_half(rph[(wave << 6) + lane]));
    float awc = aw[lane & 15];
    float abl = ab[0] * LOG2E;                // exp2-domain offset for softmax
    __half2 k_pk    = __float2half2_rn(0.5f * LOG2E);
    __half2 rpk_pk  = __float2half2_rn(rp * 0.5f * LOG2E);
    __half2 aw_pk   = __float2half2_rn(awc);
    __half2 rpa_pk  = __float2half2_rn(rp * awc);
    __half2 ones    = __float2half2_rn(1.0f);
    __half2 neg2    = __float2half2_rn(-2.0f);
    float l = 0.f, acc = 0.f;
    int i = 0;
    for (; i + 8 <= deg; i += 8) {
        int o_[8];
        unsigned short su[8];
#pragma unroll
        for (int j = 0; j < 8; ++j) o_[j] = __builtin_amdgcn_readlane(myoff, i + j);
#pragma unroll
        for (int j = 0; j < 8; ++j) su[j] = *(const unsigned short*)(splb + o_[j]);
#pragma unroll
        for (int j = 0; j < 4; ++j) {
            __half2 sp  = __halves2half2(__ushort_as_half(su[2 * j]),
                                         __ushort_as_half(su[2 * j + 1]));
            __half2 arg = __hfma2(sp, k_pk, rpk_pk);
            __half2 t2  = h2exp2(arg);
            __half2 w   = __hmul2(t2, t2);             // e^(sp+rp)
            __half2 u   = __hadd2(w, ones);
            __half2 den = __hfma2(u, u, ones);
            __half2 r   = h2rcp(den);
            __half2 f   = __hfma2(neg2, r, ones);
            __half2 za  = __hfma2(sp, aw_pk, rpa_pk);
            __half2 tt  = head_reduce_h2(__hmul2(za, f));
            float p0 = __builtin_amdgcn_exp2f(fmaf(__low2float(tt),  LOG2E, abl));
            float p1 = __builtin_amdgcn_exp2f(fmaf(__high2float(tt), LOG2E, abl));
            l += p0 + p1;
            acc = fmaf(p0, __low2float(sp), fmaf(p1, __high2float(sp), acc));
        }
    }
    for (; i + 2 <= deg; i += 2) {
        int o0 = __builtin_amdgcn_readlane(myoff, i);
        int o1 = __builtin_amdgcn_readlane(myoff, i + 1);
        __half2 sp  = __halves2half2(__ushort_as_half(*(const unsigned short*)(splb + o0)),
                                     __ushort_as_half(*(const unsigned short*)(splb + o1)));
        __half2 arg = __hfma2(sp, k_pk, rpk_pk);
        __half2 t2  = h2exp2(arg);
        __half2 w   = __hmul2(t2, t2);
        __half2 u   = __hadd2(w, ones);
        __half2 den = __hfma2(u, u, ones);
        __half2 r   = h2rcp(den);
        __half2 f   = __hfma2(neg2, r, ones);
        __half2 za  = __hfma2(sp, aw_pk, rpa_pk);
        __half2 tt  = head_reduce_h2(__hmul2(za, f));
        float p0 = __builtin_amdgcn_exp2f(fmaf(__low2float(tt),  LOG2E, abl));
        float p1 = __builtin_amdgcn_exp2f(fmaf(__high2float(tt), LOG2E, abl));
        l += p0 + p1;
        acc = fmaf(p0, __low2float(sp), fmaf(p1, __high2float(sp), acc));
    }
    if (i < deg) {
        int o0 = __builtin_amdgcn_readlane(myoff, i);
        float sp0 = __half2float(__ushort_as_half(*(const unsigned short*)(splb + o0)));
        float t0 = head_reduce(mish_aw(sp0 + rp, awc));
        float p = __builtin_amdgcn_exp2f(fmaf(t0, LOG2E, abl));
        l += p;
        acc = fmaf(p, sp0, acc);
    }
    out[(wave << 6) + lane] = (deg > 0) ? acc * __builtin_amdgcn_rcpf(l) : 0.f;
}

extern "C" void kernel_launch(void* const* d_in, const int* in_sizes, int n_in,
                              void* d_out, int out_size, void* d_ws, size_t ws_size,
                              hipStream_t stream) {
    const float* x  = (const float*)d_in[0];
    const float* Ws = (const float*)d_in[1];
    const float* bs = (const float*)d_in[2];
    const float* Wr = (const float*)d_in[3];
    const float* br = (const float*)d_in[4];
    const float* aw = (const float*)d_in[5];
    const float* ab = (const float*)d_in[6];
    const int* senders   = (const int*)d_in[7];
    const int* receivers = (const int*)d_in[8];
    float* out = (float*)d_out;

    // Workspace layout (~51.6 MB):
    char* wsp = (char*)d_ws;
    unsigned short* sph = (unsigned short*)wsp;  wsp += (size_t)N_NODES * EMBED * 2;  // 12.8 MB
    unsigned short* rph = (unsigned short*)wsp;  wsp += (size_t)N_NODES * EMBED * 2;  // 12.8 MB
    int* csr      = (int*)wsp;    wsp += (size_t)N_NODES * SLOTS * 4;    // 25.6 MB
    int* cursor   = (int*)wsp;    wsp += (size_t)N_NODES * 4;            // 0.4 MB

    // cursor must start at 0 every call (doubles as the degree array afterwards)
    hipMemsetAsync(cursor, 0, (size_t)N_NODES * 4, stream);

    proj_kernel<<<N_NODES / 16, 256, 0, stream>>>(x, Ws, bs, Wr, br, sph, rph);

    fill_kernel<<<NR * NCHUNK, 256, 0, stream>>>(senders, receivers, cursor, csr);

    int gather_blocks = (N_NODES * 64 + 255) / 256;
    fused_gather_kernel<<<gather_blocks, 256, 0, stream>>>(sph, rph, csr, cursor,
                                                           aw, ab, out);
}

// Round 12
// 172.924 us; speedup vs baseline: 1.1789x; 1.0807x over previous
//
#include <hip/hip_runtime.h>
#include <hip/hip_fp16.h>
#include <math.h>

#define N_NODES 100000
#define N_EDGES 1600000
#define EMBED 64
#define HEADS 4
#define HDIM 16

// Padded CSR: 64 slots per node (degree is Poisson(16); max over 100K nodes < 50)
#define SLOTS 64

// Two-phase bucket partition (replaces global returning-atomic fill):
#define BKT_SHIFT 10
#define BKT_NODES 1024                        // receivers per bucket
#define NBKT 98                               // ceil(100000/1024)
#define BKT_CAP 20480                         // mean 16384 + 32 sigma
#define TILE 1024                             // edges per phase-A block
#define NTILE ((N_EDGES + TILE - 1) / TILE)   // 1563

#define LOG2E 1.44269504f

// Scalar-tail mish: tanh(softplus(z)) = 1 - 2/((1+e^z)^2 + 1); returns mish(z)*awc.
__device__ __forceinline__ float mish_aw(float z, float awc) {
    float ex  = __expf(fminf(z, 30.f));
    float u   = 1.f + ex;
    float den = fmaf(u, u, 1.f);
    float f   = fmaf(-2.f, __builtin_amdgcn_rcpf(den), 1.f);
    return z * awc * f;
}

// f32 DPP rotate-add: sum-reduce + broadcast across each 16-lane head group.
template<int CTRL>
__device__ __forceinline__ float ror_add(float t) {
    int x = __builtin_amdgcn_mov_dpp(__float_as_int(t), CTRL, 0xF, 0xF, true);
    return t + __int_as_float(x);
}
__device__ __forceinline__ float head_reduce(float t) {
    t = ror_add<0x121>(t);   // row_ror:1
    t = ror_add<0x122>(t);   // row_ror:2
    t = ror_add<0x124>(t);   // row_ror:4
    t = ror_add<0x128>(t);   // row_ror:8
    return t;
}

// Packed-f16 DPP rotate-add: reduces BOTH halves (two edges) at once.
template<int CTRL>
__device__ __forceinline__ __half2 hror_add(__half2 t) {
    int x = __builtin_amdgcn_mov_dpp(__builtin_bit_cast(int, t), CTRL, 0xF, 0xF, true);
    return __hadd2(t, __builtin_bit_cast(__half2, x));
}
__device__ __forceinline__ __half2 head_reduce_h2(__half2 t) {
    t = hror_add<0x121>(t);
    t = hror_add<0x122>(t);
    t = hror_add<0x124>(t);
    t = hror_add<0x128>(t);
    return t;
}

// ---------------- Kernel 1: node projections, LDS-staged register-blocked GEMM.
// Outputs stored as f16 (error budget is bf16-grade): sph/rph, 2 B per element.
__global__ __launch_bounds__(256) void proj_kernel(
        const float* __restrict__ x,
        const float* __restrict__ Ws, const float* __restrict__ bs,
        const float* __restrict__ Wr, const float* __restrict__ br,
        unsigned short* __restrict__ sph, unsigned short* __restrict__ rph) {
    __shared__ float wsT[64 * 68];
    __shared__ float wrT[64 * 68];
    __shared__ float xsh[16 * 68];
    int tid = threadIdx.x;
    for (int i = tid; i < 4096; i += 256) {
        int k = i >> 6, o = i & 63;
        wsT[o * 68 + k] = Ws[i];
        wrT[o * 68 + k] = Wr[i];
    }
    int nb = blockIdx.x << 4;
    {
        float4 v = ((const float4*)(x + ((size_t)nb << 6)))[tid];
        int n  = tid >> 4;
        int k4 = tid & 15;
        *(float4*)(xsh + n * 68 + (k4 << 2)) = v;
    }
    __syncthreads();
    int o = tid & 63;
    int w = tid >> 6;
    float bsv = bs[o], brv = br[o];
    float accs[4], accr[4];
#pragma unroll
    for (int p = 0; p < 4; ++p) { accs[p] = bsv; accr[p] = brv; }
    const float4* ws4 = (const float4*)wsT + o * 17;
    const float4* wr4 = (const float4*)wrT + o * 17;
    const float4* xs4 = (const float4*)xsh + (w << 2) * 17;
#pragma unroll
    for (int k4 = 0; k4 < 16; ++k4) {
        float4 a = ws4[k4];
        float4 b = wr4[k4];
#pragma unroll
        for (int p = 0; p < 4; ++p) {
            float4 xv = xs4[p * 17 + k4];    // wave-uniform broadcast
            accs[p] += xv.x * a.x + xv.y * a.y + xv.z * a.z + xv.w * a.w;
            accr[p] += xv.x * b.x + xv.y * b.y + xv.z * b.z + xv.w * b.w;
        }
    }
#pragma unroll
    for (int p = 0; p < 4; ++p) {
        int node = nb + (w << 2) + p;
        sph[(node << 6) + o] = __half_as_ushort(__float2half_rn(accs[p]));
        rph[(node << 6) + o] = __half_as_ushort(__float2half_rn(accr[p]));
    }
}

// ---------------- Phase A: bucket partition of edges by receiver range.
// LDS histogram -> ONE global returning atomic per (tile,bucket) -> LDS-ranked
// scatter of packed (r_local<<17 | sender) into per-bucket arrays. Same-tile
// entries land in consecutive slots (line-friendly writes).
__global__ __launch_bounds__(256) void bucketa_kernel(
        const int* __restrict__ senders, const int* __restrict__ receivers,
        int* __restrict__ bktcnt, int* __restrict__ bkt) {
    __shared__ int hist[NBKT];
    __shared__ int base[NBKT];
    __shared__ int cur[NBKT];
    int tid = threadIdx.x;
    if (tid < NBKT) hist[tid] = 0;
    __syncthreads();
    int e0 = blockIdx.x * TILE + tid * 4;
    int4 r, s;
    bool valid = (e0 + 4 <= N_EDGES);
    if (valid) {
        r = *(const int4*)(receivers + e0);
        s = *(const int4*)(senders + e0);
        atomicAdd(&hist[r.x >> BKT_SHIFT], 1);
        atomicAdd(&hist[r.y >> BKT_SHIFT], 1);
        atomicAdd(&hist[r.z >> BKT_SHIFT], 1);
        atomicAdd(&hist[r.w >> BKT_SHIFT], 1);
    }
    __syncthreads();
    if (tid < NBKT) {
        int h = hist[tid];
        base[tid] = (h > 0) ? atomicAdd(&bktcnt[tid], h) : 0;
        cur[tid] = 0;
    }
    __syncthreads();
    if (valid) {
        int b, rk, slot;
        b = r.x >> BKT_SHIFT; rk = atomicAdd(&cur[b], 1); slot = base[b] + rk;
        if (slot < BKT_CAP) bkt[b * BKT_CAP + slot] = ((r.x & (BKT_NODES - 1)) << 17) | s.x;
        b = r.y >> BKT_SHIFT; rk = atomicAdd(&cur[b], 1); slot = base[b] + rk;
        if (slot < BKT_CAP) bkt[b * BKT_CAP + slot] = ((r.y & (BKT_NODES - 1)) << 17) | s.y;
        b = r.z >> BKT_SHIFT; rk = atomicAdd(&cur[b], 1); slot = base[b] + rk;
        if (slot < BKT_CAP) bkt[b * BKT_CAP + slot] = ((r.z & (BKT_NODES - 1)) << 17) | s.z;
        b = r.w >> BKT_SHIFT; rk = atomicAdd(&cur[b], 1); slot = base[b] + rk;
        if (slot < BKT_CAP) bkt[b * BKT_CAP + slot] = ((r.w & (BKT_NODES - 1)) << 17) | s.w;
    }
}

// ---------------- Phase B: per-bucket CSR fill with LDS cursors (no global
// returning atomics). csr[r*64+slot] = sender*128 (byte offset into f16 rows);
// cursor[] (true degree) written coalesced at the end -> no cursor memset.
__global__ __launch_bounds__(512) void bucketb_kernel(
        const int* __restrict__ bktcnt, const int* __restrict__ bkt,
        int* __restrict__ cursor, int* __restrict__ csr) {
    __shared__ int lcur[BKT_NODES];
    int tid = threadIdx.x;
    int b = blockIdx.x;
    for (int i = tid; i < BKT_NODES; i += 512) lcur[i] = 0;
    __syncthreads();
    int cnt = bktcnt[b];
    if (cnt > BKT_CAP) cnt = BKT_CAP;
    const int* bb = bkt + b * BKT_CAP;
    for (int i = tid; i < cnt; i += 512) {
        int v = bb[i];
        int rl = v >> 17;
        int sv = v & 0x1FFFF;
        int slot = atomicAdd(&lcur[rl], 1);
        if (slot < SLOTS) csr[((((b << BKT_SHIFT) + rl)) << 6) + slot] = sv << 7;
    }
    __syncthreads();
    int nbase = b << BKT_SHIFT;
    for (int i = tid; i < BKT_NODES; i += 512) {
        int node = nbase + i;
        if (node < N_NODES) cursor[node] = lcur[i];
    }
}

// ---------------- Fused per-node: logits + softmax + weighted gather.
// One wave per node; lane = output element (h*16+d). f16 tables (12.8 MB each)
// halve the per-XCD L2-fill replication. Per-lane CSR preload + readlane
// broadcast removes all wave-uniform csr loads from the loop.
__global__ __launch_bounds__(256) void fused_gather_kernel(
                                    const unsigned short* __restrict__ sph,
                                    const unsigned short* __restrict__ rph,
                                    const int* __restrict__ csr,
                                    const int* __restrict__ cursor,
                                    const float* __restrict__ aw,
                                    const float* __restrict__ ab,
                                    float* __restrict__ out) {
    int wave = (blockIdx.x * blockDim.x + threadIdx.x) >> 6;   // grid covers exactly N_NODES
    int lane = threadIdx.x & 63;
    int deg = cursor[wave];
    deg = (deg > SLOTS) ? SLOTS : deg;
    int myoff = csr[(wave << 6) + lane];      // this lane's slot of the csr row
    const char* splb = (const char*)sph + (lane << 1);   // csr holds byte offsets
    float rp  = __half2float(__ushort_as_half(rph[(wave << 6) + lane]));
    float awc = aw[lane & 15];
    float abl = ab[0] * LOG2E;                // exp2-domain offset for softmax
    __half2 k_pk    = __float2half2_rn(0.5f * LOG2E);
    __half2 rpk_pk  = __float2half2_rn(rp * 0.5f * LOG2E);
    __half2 aw_pk   = __float2half2_rn(awc);
    __half2 rpa_pk  = __float2half2_rn(rp * awc);
    __half2 ones    = __float2half2_rn(1.0f);
    __half2 neg2    = __float2half2_rn(-2.0f);
    float l = 0.f, acc = 0.f;
    int i = 0;
    for (; i + 8 <= deg; i += 8) {
        int o_[8];
        unsigned short su[8];
#pragma unroll
        for (int j = 0; j < 8; ++j) o_[j] = __builtin_amdgcn_readlane(myoff, i + j);
#pragma unroll
        for (int j = 0; j < 8; ++j) su[j] = *(const unsigned short*)(splb + o_[j]);
#pragma unroll
        for (int j = 0; j < 4; ++j) {
            __half2 sp  = __halves2half2(__ushort_as_half(su[2 * j]),
                                         __ushort_as_half(su[2 * j + 1]));
            __half2 arg = __hfma2(sp, k_pk, rpk_pk);
            __half2 t2  = h2exp2(arg);
            __half2 w   = __hmul2(t2, t2);             // e^(sp+rp)
            __half2 u   = __hadd2(w, ones);
            __half2 den = __hfma2(u, u, ones);
            __half2 r   = h2rcp(den);
            __half2 f   = __hfma2(neg2, r, ones);
            __half2 za  = __hfma2(sp, aw_pk, rpa_pk);
            __half2 tt  = head_reduce_h2(__hmul2(za, f));
            float p0 = __builtin_amdgcn_exp2f(fmaf(__low2float(tt),  LOG2E, abl));
            float p1 = __builtin_amdgcn_exp2f(fmaf(__high2float(tt), LOG2E, abl));
            l += p0 + p1;
            acc = fmaf(p0, __low2float(sp), fmaf(p1, __high2float(sp), acc));
        }
    }
    for (; i + 2 <= deg; i += 2) {
        int o0 = __builtin_amdgcn_readlane(myoff, i);
        int o1 = __builtin_amdgcn_readlane(myoff, i + 1);
        __half2 sp  = __halves2half2(__ushort_as_half(*(const unsigned short*)(splb + o0)),
                                     __ushort_as_half(*(const unsigned short*)(splb + o1)));
        __half2 arg = __hfma2(sp, k_pk, rpk_pk);
        __half2 t2  = h2exp2(arg);
        __half2 w   = __hmul2(t2, t2);
        __half2 u   = __hadd2(w, ones);
        __half2 den = __hfma2(u, u, ones);
        __half2 r   = h2rcp(den);
        __half2 f   = __hfma2(neg2, r, ones);
        __half2 za  = __hfma2(sp, aw_pk, rpa_pk);
        __half2 tt  = head_reduce_h2(__hmul2(za, f));
        float p0 = __builtin_amdgcn_exp2f(fmaf(__low2float(tt),  LOG2E, abl));
        float p1 = __builtin_amdgcn_exp2f(fmaf(__high2float(tt), LOG2E, abl));
        l += p0 + p1;
        acc = fmaf(p0, __low2float(sp), fmaf(p1, __high2float(sp), acc));
    }
    if (i < deg) {
        int o0 = __builtin_amdgcn_readlane(myoff, i);
        float sp0 = __half2float(__ushort_as_half(*(const unsigned short*)(splb + o0)));
        float t0 = head_reduce(mish_aw(sp0 + rp, awc));
        float p = __builtin_amdgcn_exp2f(fmaf(t0, LOG2E, abl));
        l += p;
        acc = fmaf(p, sp0, acc);
    }
    out[(wave << 6) + lane] = (deg > 0) ? acc * __builtin_amdgcn_rcpf(l) : 0.f;
}

extern "C" void kernel_launch(void* const* d_in, const int* in_sizes, int n_in,
                              void* d_out, int out_size, void* d_ws, size_t ws_size,
                              hipStream_t stream) {
    const float* x  = (const float*)d_in[0];
    const float* Ws = (const float*)d_in[1];
    const float* bs = (const float*)d_in[2];
    const float* Wr = (const float*)d_in[3];
    const float* br = (const float*)d_in[4];
    const float* aw = (const float*)d_in[5];
    const float* ab = (const float*)d_in[6];
    const int* senders   = (const int*)d_in[7];
    const int* receivers = (const int*)d_in[8];
    float* out = (float*)d_out;

    // Workspace layout (~60 MB):
    char* wsp = (char*)d_ws;
    unsigned short* sph = (unsigned short*)wsp;  wsp += (size_t)N_NODES * EMBED * 2;  // 12.8 MB
    unsigned short* rph = (unsigned short*)wsp;  wsp += (size_t)N_NODES * EMBED * 2;  // 12.8 MB
    int* csr    = (int*)wsp;  wsp += (size_t)N_NODES * SLOTS * 4;    // 25.6 MB
    int* cursor = (int*)wsp;  wsp += (size_t)N_NODES * 4;            // 0.4 MB
    int* bkt    = (int*)wsp;  wsp += (size_t)NBKT * BKT_CAP * 4;     // 8.0 MB
    int* bktcnt = (int*)wsp;  wsp += 128 * 4;

    hipMemsetAsync(bktcnt, 0, NBKT * 4, stream);

    proj_kernel<<<N_NODES / 16, 256, 0, stream>>>(x, Ws, bs, Wr, br, sph, rph);

    bucketa_kernel<<<NTILE, 256, 0, stream>>>(senders, receivers, bktcnt, bkt);
    bucketb_kernel<<<NBKT, 512, 0, stream>>>(bktcnt, bkt, cursor, csr);

    int gather_blocks = (N_NODES * 64 + 255) / 256;
    fused_gather_kernel<<<gather_blocks, 256, 0, stream>>>(sph, rph, csr, cursor,
                                                           aw, ab, out);
}

// Round 13
// 145.119 us; speedup vs baseline: 1.4048x; 1.1916x over previous
//
#include <hip/hip_runtime.h>
#include <hip/hip_fp16.h>
#include <math.h>

#define N_NODES 100000
#define N_EDGES 1600000
#define EMBED 64
#define HEADS 4
#define HDIM 16

// Padded CSR: 64 slots per node (degree is Poisson(16); max over 100K nodes < 50)
#define SLOTS 64

// Two-phase bucket partition (no global returning atomics on the hot path):
#define BKT_SHIFT 8
#define BKT_NODES 256                         // receivers per bucket
#define NBKT 391                              // ceil(100000/256)
#define BKT_CAP 5120                          // mean 4092 + 16 sigma
#define TILE 4096                             // edges per phase-A block
#define NTILE 391                             // ceil(1600000/4096)
#define NGRP (N_EDGES / 4)                    // 400000 int4 groups

#define LOG2E 1.44269504f

// Scalar-tail mish: tanh(softplus(z)) = 1 - 2/((1+e^z)^2 + 1); returns mish(z)*awc.
__device__ __forceinline__ float mish_aw(float z, float awc) {
    float ex  = __expf(fminf(z, 30.f));
    float u   = 1.f + ex;
    float den = fmaf(u, u, 1.f);
    float f   = fmaf(-2.f, __builtin_amdgcn_rcpf(den), 1.f);
    return z * awc * f;
}

// f32 DPP rotate-add: sum-reduce + broadcast across each 16-lane head group.
template<int CTRL>
__device__ __forceinline__ float ror_add(float t) {
    int x = __builtin_amdgcn_mov_dpp(__float_as_int(t), CTRL, 0xF, 0xF, true);
    return t + __int_as_float(x);
}
__device__ __forceinline__ float head_reduce(float t) {
    t = ror_add<0x121>(t);   // row_ror:1
    t = ror_add<0x122>(t);   // row_ror:2
    t = ror_add<0x124>(t);   // row_ror:4
    t = ror_add<0x128>(t);   // row_ror:8
    return t;
}

// Packed-f16 DPP rotate-add: reduces BOTH halves (two edges) at once.
template<int CTRL>
__device__ __forceinline__ __half2 hror_add(__half2 t) {
    int x = __builtin_amdgcn_mov_dpp(__builtin_bit_cast(int, t), CTRL, 0xF, 0xF, true);
    return __hadd2(t, __builtin_bit_cast(__half2, x));
}
__device__ __forceinline__ __half2 head_reduce_h2(__half2 t) {
    t = hror_add<0x121>(t);
    t = hror_add<0x122>(t);
    t = hror_add<0x124>(t);
    t = hror_add<0x128>(t);
    return t;
}

// ---------------- Kernel 1: node projections, LDS-staged register-blocked GEMM.
// Outputs stored as f16 (error budget is bf16-grade): sph/rph, 2 B per element.
__global__ __launch_bounds__(256) void proj_kernel(
        const float* __restrict__ x,
        const float* __restrict__ Ws, const float* __restrict__ bs,
        const float* __restrict__ Wr, const float* __restrict__ br,
        unsigned short* __restrict__ sph, unsigned short* __restrict__ rph) {
    __shared__ float wsT[64 * 68];
    __shared__ float wrT[64 * 68];
    __shared__ float xsh[16 * 68];
    int tid = threadIdx.x;
    for (int i = tid; i < 4096; i += 256) {
        int k = i >> 6, o = i & 63;
        wsT[o * 68 + k] = Ws[i];
        wrT[o * 68 + k] = Wr[i];
    }
    int nb = blockIdx.x << 4;
    {
        float4 v = ((const float4*)(x + ((size_t)nb << 6)))[tid];
        int n  = tid >> 4;
        int k4 = tid & 15;
        *(float4*)(xsh + n * 68 + (k4 << 2)) = v;
    }
    __syncthreads();
    int o = tid & 63;
    int w = tid >> 6;
    float bsv = bs[o], brv = br[o];
    float accs[4], accr[4];
#pragma unroll
    for (int p = 0; p < 4; ++p) { accs[p] = bsv; accr[p] = brv; }
    const float4* ws4 = (const float4*)wsT + o * 17;
    const float4* wr4 = (const float4*)wrT + o * 17;
    const float4* xs4 = (const float4*)xsh + (w << 2) * 17;
#pragma unroll
    for (int k4 = 0; k4 < 16; ++k4) {
        float4 a = ws4[k4];
        float4 b = wr4[k4];
#pragma unroll
        for (int p = 0; p < 4; ++p) {
            float4 xv = xs4[p * 17 + k4];    // wave-uniform broadcast
            accs[p] += xv.x * a.x + xv.y * a.y + xv.z * a.z + xv.w * a.w;
            accr[p] += xv.x * b.x + xv.y * b.y + xv.z * b.z + xv.w * b.w;
        }
    }
#pragma unroll
    for (int p = 0; p < 4; ++p) {
        int node = nb + (w << 2) + p;
        sph[(node << 6) + o] = __half_as_ushort(__float2half_rn(accs[p]));
        rph[(node << 6) + o] = __half_as_ushort(__float2half_rn(accr[p]));
    }
}

// ---------------- Phase A: bucket partition of edges by receiver range.
// LDS histogram -> ONE global returning atomic per (tile,bucket) -> LDS-ranked
// scatter of packed ((r&255)<<17 | sender) into per-bucket arrays.
__global__ __launch_bounds__(256) void bucketa_kernel(
        const int* __restrict__ senders, const int* __restrict__ receivers,
        int* __restrict__ bktcnt, int* __restrict__ bkt) {
    __shared__ int hist[NBKT];
    __shared__ int base[NBKT];
    __shared__ int cur[NBKT];
    int tid = threadIdx.x;
    for (int i = tid; i < NBKT; i += 256) hist[i] = 0;
    __syncthreads();
    int g0 = blockIdx.x * (TILE / 4);
    int4 r[4], s[4];
    bool v[4];
#pragma unroll
    for (int t = 0; t < 4; ++t) {
        int g = g0 + t * 256 + tid;
        v[t] = (g < NGRP);
        if (v[t]) {
            r[t] = ((const int4*)receivers)[g];
            s[t] = ((const int4*)senders)[g];
            atomicAdd(&hist[r[t].x >> BKT_SHIFT], 1);
            atomicAdd(&hist[r[t].y >> BKT_SHIFT], 1);
            atomicAdd(&hist[r[t].z >> BKT_SHIFT], 1);
            atomicAdd(&hist[r[t].w >> BKT_SHIFT], 1);
        }
    }
    __syncthreads();
    for (int i = tid; i < NBKT; i += 256) {
        int h = hist[i];
        base[i] = (h > 0) ? atomicAdd(&bktcnt[i], h) : 0;
        cur[i] = 0;
    }
    __syncthreads();
#pragma unroll
    for (int t = 0; t < 4; ++t) {
        if (v[t]) {
            int b, rk, slot;
            b = r[t].x >> BKT_SHIFT; rk = atomicAdd(&cur[b], 1); slot = base[b] + rk;
            if (slot < BKT_CAP) bkt[b * BKT_CAP + slot] = ((r[t].x & (BKT_NODES - 1)) << 17) | s[t].x;
            b = r[t].y >> BKT_SHIFT; rk = atomicAdd(&cur[b], 1); slot = base[b] + rk;
            if (slot < BKT_CAP) bkt[b * BKT_CAP + slot] = ((r[t].y & (BKT_NODES - 1)) << 17) | s[t].y;
            b = r[t].z >> BKT_SHIFT; rk = atomicAdd(&cur[b], 1); slot = base[b] + rk;
            if (slot < BKT_CAP) bkt[b * BKT_CAP + slot] = ((r[t].z & (BKT_NODES - 1)) << 17) | s[t].z;
            b = r[t].w >> BKT_SHIFT; rk = atomicAdd(&cur[b], 1); slot = base[b] + rk;
            if (slot < BKT_CAP) bkt[b * BKT_CAP + slot] = ((r[t].w & (BKT_NODES - 1)) << 17) | s[t].w;
        }
    }
}

// ---------------- Phase B: per-bucket CSR fill with LDS cursors.
// 391 blocks x 1024 threads (~4 iterations each). csr[r*64+slot] = sender*128;
// cursor[] (true degree) written at the end -> no cursor memset.
__global__ __launch_bounds__(1024) void bucketb_kernel(
        const int* __restrict__ bktcnt, const int* __restrict__ bkt,
        int* __restrict__ cursor, int* __restrict__ csr) {
    __shared__ int lcur[BKT_NODES];
    int tid = threadIdx.x;
    int b = blockIdx.x;
    if (tid < BKT_NODES) lcur[tid] = 0;
    __syncthreads();
    int cnt = bktcnt[b];
    if (cnt > BKT_CAP) cnt = BKT_CAP;
    const int* bb = bkt + b * BKT_CAP;
    for (int i = tid; i < cnt; i += 1024) {
        int vv = bb[i];
        int rl = vv >> 17;
        int sv = vv & 0x1FFFF;
        int slot = atomicAdd(&lcur[rl], 1);
        if (slot < SLOTS) csr[((((b << BKT_SHIFT) + rl)) << 6) + slot] = sv << 7;
    }
    __syncthreads();
    if (tid < BKT_NODES) {
        int node = (b << BKT_SHIFT) + tid;
        if (node < N_NODES) cursor[node] = lcur[tid];
    }
}

// ---------------- Fused per-node: logits + softmax + weighted gather.
// One wave per node; lane = output element (h*16+d). f16 tables (12.8 MB each)
// halve the per-XCD L2-fill replication. Per-lane CSR preload + readlane
// broadcast removes all wave-uniform csr loads from the loop.
__global__ __launch_bounds__(256) void fused_gather_kernel(
                                    const unsigned short* __restrict__ sph,
                                    const unsigned short* __restrict__ rph,
                                    const int* __restrict__ csr,
                                    const int* __restrict__ cursor,
                                    const float* __restrict__ aw,
                                    const float* __restrict__ ab,
                                    float* __restrict__ out) {
    int wave = (blockIdx.x * blockDim.x + threadIdx.x) >> 6;   // grid covers exactly N_NODES
    int lane = threadIdx.x & 63;
    int deg = cursor[wave];
    deg = (deg > SLOTS) ? SLOTS : deg;
    int myoff = csr[(wave << 6) + lane];      // this lane's slot of the csr row
    const char* splb = (const char*)sph + (lane << 1);   // csr holds byte offsets
    float rp  = __half2float(__ushort_as_half(rph[(wave << 6) + lane]));
    float awc = aw[lane & 15];
    float abl = ab[0] * LOG2E;                // exp2-domain offset for softmax
    __half2 k_pk    = __float2half2_rn(0.5f * LOG2E);
    __half2 rpk_pk  = __float2half2_rn(rp * 0.5f * LOG2E);
    __half2 aw_pk   = __float2half2_rn(awc);
    __half2 rpa_pk  = __float2half2_rn(rp * awc);
    __half2 ones    = __float2half2_rn(1.0f);
    __half2 neg2    = __float2half2_rn(-2.0f);
    float l = 0.f, acc = 0.f;
    int i = 0;
    for (; i + 8 <= deg; i += 8) {
        int o_[8];
        unsigned short su[8];
#pragma unroll
        for (int j = 0; j < 8; ++j) o_[j] = __builtin_amdgcn_readlane(myoff, i + j);
#pragma unroll
        for (int j = 0; j < 8; ++j) su[j] = *(const unsigned short*)(splb + o_[j]);
#pragma unroll
        for (int j = 0; j < 4; ++j) {
            __half2 sp  = __halves2half2(__ushort_as_half(su[2 * j]),
                                         __ushort_as_half(su[2 * j + 1]));
            __half2 arg = __hfma2(sp, k_pk, rpk_pk);
            __half2 t2  = h2exp2(arg);
            __half2 w   = __hmul2(t2, t2);             // e^(sp+rp)
            __half2 u   = __hadd2(w, ones);
            __half2 den = __hfma2(u, u, ones);
            __half2 r   = h2rcp(den);
            __half2 f   = __hfma2(neg2, r, ones);
            __half2 za  = __hfma2(sp, aw_pk, rpa_pk);
            __half2 tt  = head_reduce_h2(__hmul2(za, f));
            float p0 = __builtin_amdgcn_exp2f(fmaf(__low2float(tt),  LOG2E, abl));
            float p1 = __builtin_amdgcn_exp2f(fmaf(__high2float(tt), LOG2E, abl));
            l += p0 + p1;
            acc = fmaf(p0, __low2float(sp), fmaf(p1, __high2float(sp), acc));
        }
    }
    for (; i + 2 <= deg; i += 2) {
        int o0 = __builtin_amdgcn_readlane(myoff, i);
        int o1 = __builtin_amdgcn_readlane(myoff, i + 1);
        __half2 sp  = __halves2half2(__ushort_as_half(*(const unsigned short*)(splb + o0)),
                                     __ushort_as_half(*(const unsigned short*)(splb + o1)));
        __half2 arg = __hfma2(sp, k_pk, rpk_pk);
        __half2 t2  = h2exp2(arg);
        __half2 w   = __hmul2(t2, t2);
        __half2 u   = __hadd2(w, ones);
        __half2 den = __hfma2(u, u, ones);
        __half2 r   = h2rcp(den);
        __half2 f   = __hfma2(neg2, r, ones);
        __half2 za  = __hfma2(sp, aw_pk, rpa_pk);
        __half2 tt  = head_reduce_h2(__hmul2(za, f));
        float p0 = __builtin_amdgcn_exp2f(fmaf(__low2float(tt),  LOG2E, abl));
        float p1 = __builtin_amdgcn_exp2f(fmaf(__high2float(tt), LOG2E, abl));
        l += p0 + p1;
        acc = fmaf(p0, __low2float(sp), fmaf(p1, __high2float(sp), acc));
    }
    if (i < deg) {
        int o0 = __builtin_amdgcn_readlane(myoff, i);
        float sp0 = __half2float(__ushort_as_half(*(const unsigned short*)(splb + o0)));
        float t0 = head_reduce(mish_aw(sp0 + rp, awc));
        float p = __builtin_amdgcn_exp2f(fmaf(t0, LOG2E, abl));
        l += p;
        acc = fmaf(p, sp0, acc);
    }
    out[(wave << 6) + lane] = (deg > 0) ? acc * __builtin_amdgcn_rcpf(l) : 0.f;
}

extern "C" void kernel_launch(void* const* d_in, const int* in_sizes, int n_in,
                              void* d_out, int out_size, void* d_ws, size_t ws_size,
                              hipStream_t stream) {
    const float* x  = (const float*)d_in[0];
    const float* Ws = (const float*)d_in[1];
    const float* bs = (const float*)d_in[2];
    const float* Wr = (const float*)d_in[3];
    const float* br = (const float*)d_in[4];
    const float* aw = (const float*)d_in[5];
    const float* ab = (const float*)d_in[6];
    const int* senders   = (const int*)d_in[7];
    const int* receivers = (const int*)d_in[8];
    float* out = (float*)d_out;

    // Workspace layout (~60 MB):
    char* wsp = (char*)d_ws;
    unsigned short* sph = (unsigned short*)wsp;  wsp += (size_t)N_NODES * EMBED * 2;  // 12.8 MB
    unsigned short* rph = (unsigned short*)wsp;  wsp += (size_t)N_NODES * EMBED * 2;  // 12.8 MB
    int* csr    = (int*)wsp;  wsp += (size_t)N_NODES * SLOTS * 4;    // 25.6 MB
    int* cursor = (int*)wsp;  wsp += (size_t)N_NODES * 4;            // 0.4 MB
    int* bkt    = (int*)wsp;  wsp += (size_t)NBKT * BKT_CAP * 4;     // 8.0 MB
    int* bktcnt = (int*)wsp;  wsp += 512 * 4;

    hipMemsetAsync(bktcnt, 0, NBKT * 4, stream);

    proj_kernel<<<N_NODES / 16, 256, 0, stream>>>(x, Ws, bs, Wr, br, sph, rph);

    bucketa_kernel<<<NTILE, 256, 0, stream>>>(senders, receivers, bktcnt, bkt);
    bucketb_kernel<<<NBKT, 1024, 0, stream>>>(bktcnt, bkt, cursor, csr);

    int gather_blocks = (N_NODES * 64 + 255) / 256;
    fused_gather_kernel<<<gather_blocks, 256, 0, stream>>>(sph, rph, csr, cursor,
                                                           aw, ab, out);
}

// Round 14
// 133.454 us; speedup vs baseline: 1.5276x; 1.0874x over previous
//
#include <hip/hip_runtime.h>
#include <hip/hip_fp16.h>
#include <math.h>

#define N_NODES 100000
#define N_EDGES 1600000
#define EMBED 64
#define HEADS 4
#define HDIM 16

// Padded CSR: 64 slots per node (degree is Poisson(16); max over 100K nodes < 50)
#define SLOTS 64

// Two-phase bucket partition (no global returning atomics on the hot path):
#define BKT_SHIFT 8
#define BKT_NODES 256                         // receivers per bucket
#define NBKT 391                              // ceil(100000/256)
#define BKT_CAP 5120                          // mean 4096 + 16 sigma
#define TILE 4096                             // edges per bucketa-role block
#define NTILE 391                             // ceil(1600000/4096)
#define NGRP (N_EDGES / 4)                    // 400000 int4 groups

#define NBLK_PROJ (N_NODES / 16)              // 6250
#define SMEM_BYTES 39168                      // proj role: (2*64*68 + 16*68) * 4

#define LOG2E 1.44269504f

// Scalar-tail mish: tanh(softplus(z)) = 1 - 2/((1+e^z)^2 + 1); returns mish(z)*awc.
__device__ __forceinline__ float mish_aw(float z, float awc) {
    float ex  = __expf(fminf(z, 30.f));
    float u   = 1.f + ex;
    float den = fmaf(u, u, 1.f);
    float f   = fmaf(-2.f, __builtin_amdgcn_rcpf(den), 1.f);
    return z * awc * f;
}

// f32 DPP rotate-add: sum-reduce + broadcast across each 16-lane head group.
template<int CTRL>
__device__ __forceinline__ float ror_add(float t) {
    int x = __builtin_amdgcn_mov_dpp(__float_as_int(t), CTRL, 0xF, 0xF, true);
    return t + __int_as_float(x);
}
__device__ __forceinline__ float head_reduce(float t) {
    t = ror_add<0x121>(t);   // row_ror:1
    t = ror_add<0x122>(t);   // row_ror:2
    t = ror_add<0x124>(t);   // row_ror:4
    t = ror_add<0x128>(t);   // row_ror:8
    return t;
}

// Packed-f16 DPP rotate-add: reduces BOTH halves (two edges) at once.
template<int CTRL>
__device__ __forceinline__ __half2 hror_add(__half2 t) {
    int x = __builtin_amdgcn_mov_dpp(__builtin_bit_cast(int, t), CTRL, 0xF, 0xF, true);
    return __hadd2(t, __builtin_bit_cast(__half2, x));
}
__device__ __forceinline__ __half2 head_reduce_h2(__half2 t) {
    t = hror_add<0x121>(t);
    t = hror_add<0x122>(t);
    t = hror_add<0x124>(t);
    t = hror_add<0x128>(t);
    return t;
}

// ---------------- Fused kernel 1: proj (blocks 0..6249) + bucketa (6250..6640).
// Roles are independent; bucketa is only 391 blocks (<2/CU) so proj's 39 KB LDS
// allocation cannot starve it (r10's failure mode needed 4000 high-occ blocks).
__global__ __launch_bounds__(256) void proj_bucketa_kernel(
        const float* __restrict__ x,
        const float* __restrict__ Ws, const float* __restrict__ bs,
        const float* __restrict__ Wr, const float* __restrict__ br,
        const int* __restrict__ senders, const int* __restrict__ receivers,
        unsigned short* __restrict__ sph, unsigned short* __restrict__ rph,
        int* __restrict__ bktcnt, int* __restrict__ bkt) {
    __shared__ __align__(16) char smem[SMEM_BYTES];
    int tid = threadIdx.x;
    if (blockIdx.x < NBLK_PROJ) {
        // ---- proj role: LDS-staged register-blocked GEMM, f16 outputs.
        float* wsT = (float*)smem;            // [64*68]
        float* wrT = wsT + 64 * 68;           // [64*68]
        float* xsh = wrT + 64 * 68;           // [16*68]
        for (int i = tid; i < 4096; i += 256) {
            int k = i >> 6, o = i & 63;
            wsT[o * 68 + k] = Ws[i];
            wrT[o * 68 + k] = Wr[i];
        }
        int nb = blockIdx.x << 4;
        {
            float4 v = ((const float4*)(x + ((size_t)nb << 6)))[tid];
            int n  = tid >> 4;
            int k4 = tid & 15;
            *(float4*)(xsh + n * 68 + (k4 << 2)) = v;
        }
        __syncthreads();
        int o = tid & 63;
        int w = tid >> 6;
        float bsv = bs[o], brv = br[o];
        float accs[4], accr[4];
#pragma unroll
        for (int p = 0; p < 4; ++p) { accs[p] = bsv; accr[p] = brv; }
        const float4* ws4 = (const float4*)wsT + o * 17;
        const float4* wr4 = (const float4*)wrT + o * 17;
        const float4* xs4 = (const float4*)xsh + (w << 2) * 17;
#pragma unroll
        for (int k4 = 0; k4 < 16; ++k4) {
            float4 a = ws4[k4];
            float4 b = wr4[k4];
#pragma unroll
            for (int p = 0; p < 4; ++p) {
                float4 xv = xs4[p * 17 + k4];    // wave-uniform broadcast
                accs[p] += xv.x * a.x + xv.y * a.y + xv.z * a.z + xv.w * a.w;
                accr[p] += xv.x * b.x + xv.y * b.y + xv.z * b.z + xv.w * b.w;
            }
        }
#pragma unroll
        for (int p = 0; p < 4; ++p) {
            int node = nb + (w << 2) + p;
            sph[(node << 6) + o] = __half_as_ushort(__float2half_rn(accs[p]));
            rph[(node << 6) + o] = __half_as_ushort(__float2half_rn(accr[p]));
        }
    } else {
        // ---- bucketa role: LDS histogram -> one global atomic per (tile,bucket)
        // -> LDS-ranked scatter of packed ((r&255)<<17 | sender).
        int* hist = (int*)smem;               // [NBKT]
        int* base = hist + NBKT;
        int* cur  = base + NBKT;
        for (int i = tid; i < NBKT; i += 256) hist[i] = 0;
        __syncthreads();
        int g0 = (blockIdx.x - NBLK_PROJ) * (TILE / 4);
        int4 r[4], s[4];
        bool v[4];
#pragma unroll
        for (int t = 0; t < 4; ++t) {
            int g = g0 + t * 256 + tid;
            v[t] = (g < NGRP);
            if (v[t]) {
                r[t] = ((const int4*)receivers)[g];
                s[t] = ((const int4*)senders)[g];
                atomicAdd(&hist[r[t].x >> BKT_SHIFT], 1);
                atomicAdd(&hist[r[t].y >> BKT_SHIFT], 1);
                atomicAdd(&hist[r[t].z >> BKT_SHIFT], 1);
                atomicAdd(&hist[r[t].w >> BKT_SHIFT], 1);
            }
        }
        __syncthreads();
        for (int i = tid; i < NBKT; i += 256) {
            int h = hist[i];
            base[i] = (h > 0) ? atomicAdd(&bktcnt[i], h) : 0;
            cur[i] = 0;
        }
        __syncthreads();
#pragma unroll
        for (int t = 0; t < 4; ++t) {
            if (v[t]) {
                int b, rk, slot;
                b = r[t].x >> BKT_SHIFT; rk = atomicAdd(&cur[b], 1); slot = base[b] + rk;
                if (slot < BKT_CAP) bkt[b * BKT_CAP + slot] = ((r[t].x & (BKT_NODES - 1)) << 17) | s[t].x;
                b = r[t].y >> BKT_SHIFT; rk = atomicAdd(&cur[b], 1); slot = base[b] + rk;
                if (slot < BKT_CAP) bkt[b * BKT_CAP + slot] = ((r[t].y & (BKT_NODES - 1)) << 17) | s[t].y;
                b = r[t].z >> BKT_SHIFT; rk = atomicAdd(&cur[b], 1); slot = base[b] + rk;
                if (slot < BKT_CAP) bkt[b * BKT_CAP + slot] = ((r[t].z & (BKT_NODES - 1)) << 17) | s[t].z;
                b = r[t].w >> BKT_SHIFT; rk = atomicAdd(&cur[b], 1); slot = base[b] + rk;
                if (slot < BKT_CAP) bkt[b * BKT_CAP + slot] = ((r[t].w & (BKT_NODES - 1)) << 17) | s[t].w;
            }
        }
    }
}

// ---------------- Phase B: per-bucket CSR fill with LDS cursors.
// 391 blocks x 1024 threads. csr[r*64+slot] = sender*128 (byte offset);
// cursor[] (true degree) written at the end -> no cursor memset.
__global__ __launch_bounds__(1024) void bucketb_kernel(
        const int* __restrict__ bktcnt, const int* __restrict__ bkt,
        int* __restrict__ cursor, int* __restrict__ csr) {
    __shared__ int lcur[BKT_NODES];
    int tid = threadIdx.x;
    int b = blockIdx.x;
    if (tid < BKT_NODES) lcur[tid] = 0;
    __syncthreads();
    int cnt = bktcnt[b];
    if (cnt > BKT_CAP) cnt = BKT_CAP;
    const int* bb = bkt + b * BKT_CAP;
    for (int i = tid; i < cnt; i += 1024) {
        int vv = bb[i];
        int rl = vv >> 17;
        int sv = vv & 0x1FFFF;
        int slot = atomicAdd(&lcur[rl], 1);
        if (slot < SLOTS) csr[((((b << BKT_SHIFT) + rl)) << 6) + slot] = sv << 7;
    }
    __syncthreads();
    if (tid < BKT_NODES) {
        int node = (b << BKT_SHIFT) + tid;
        if (node < N_NODES) cursor[node] = lcur[tid];
    }
}

// ---------------- Fused per-node: logits + softmax + weighted gather.
// One wave per node; lane = output element (h*16+d). wave id is forced scalar
// via readfirstlane so csr/cursor reads compile to s_load (SMEM pipe) instead
// of vector loads + manual v_readlane broadcasts.
__global__ __launch_bounds__(256) void fused_gather_kernel(
                                    const unsigned short* __restrict__ sph,
                                    const unsigned short* __restrict__ rph,
                                    const int* __restrict__ csr,
                                    const int* __restrict__ cursor,
                                    const float* __restrict__ aw,
                                    const float* __restrict__ ab,
                                    float* __restrict__ out) {
    int wave = (blockIdx.x * blockDim.x + threadIdx.x) >> 6;   // grid covers exactly N_NODES
    wave = __builtin_amdgcn_readfirstlane(wave);               // provably wave-uniform
    int lane = threadIdx.x & 63;
    int deg = cursor[wave];                   // scalar load
    deg = (deg > SLOTS) ? SLOTS : deg;
    const int* cbase = csr + (wave << 6);     // uniform base -> s_load rows
    const char* splb = (const char*)sph + (lane << 1);   // csr holds byte offsets
    float rp  = __half2float(__ushort_as_half(rph[(wave << 6) + lane]));
    float awc = aw[lane & 15];
    float abl = ab[0] * LOG2E;                // exp2-domain offset for softmax
    __half2 k_pk    = __float2half2_rn(0.5f * LOG2E);
    __half2 rpk_pk  = __float2half2_rn(rp * 0.5f * LOG2E);
    __half2 aw_pk   = __float2half2_rn(awc);
    __half2 rpa_pk  = __float2half2_rn(rp * awc);
    __half2 ones    = __float2half2_rn(1.0f);
    __half2 neg2    = __float2half2_rn(-2.0f);
    float l = 0.f, acc = 0.f;
    int i = 0;
    for (; i + 8 <= deg; i += 8) {
        unsigned short su[8];
#pragma unroll
        for (int j = 0; j < 8; ++j) su[j] = *(const unsigned short*)(splb + cbase[i + j]);
#pragma unroll
        for (int j = 0; j < 4; ++j) {
            __half2 sp  = __halves2half2(__ushort_as_half(su[2 * j]),
                                         __ushort_as_half(su[2 * j + 1]));
            __half2 arg = __hfma2(sp, k_pk, rpk_pk);
            __half2 t2  = h2exp2(arg);
            __half2 w   = __hmul2(t2, t2);             // e^(sp+rp)
            __half2 u   = __hadd2(w, ones);
            __half2 den = __hfma2(u, u, ones);
            __half2 r   = h2rcp(den);
            __half2 f   = __hfma2(neg2, r, ones);
            __half2 za  = __hfma2(sp, aw_pk, rpa_pk);
            __half2 tt  = head_reduce_h2(__hmul2(za, f));
            float p0 = __builtin_amdgcn_exp2f(fmaf(__low2float(tt),  LOG2E, abl));
            float p1 = __builtin_amdgcn_exp2f(fmaf(__high2float(tt), LOG2E, abl));
            l += p0 + p1;
            acc = fmaf(p0, __low2float(sp), fmaf(p1, __high2float(sp), acc));
        }
    }
    for (; i + 2 <= deg; i += 2) {
        __half2 sp  = __halves2half2(__ushort_as_half(*(const unsigned short*)(splb + cbase[i])),
                                     __ushort_as_half(*(const unsigned short*)(splb + cbase[i + 1])));
        __half2 arg = __hfma2(sp, k_pk, rpk_pk);
        __half2 t2  = h2exp2(arg);
        __half2 w   = __hmul2(t2, t2);
        __half2 u   = __hadd2(w, ones);
        __half2 den = __hfma2(u, u, ones);
        __half2 r   = h2rcp(den);
        __half2 f   = __hfma2(neg2, r, ones);
        __half2 za  = __hfma2(sp, aw_pk, rpa_pk);
        __half2 tt  = head_reduce_h2(__hmul2(za, f));
        float p0 = __builtin_amdgcn_exp2f(fmaf(__low2float(tt),  LOG2E, abl));
        float p1 = __builtin_amdgcn_exp2f(fmaf(__high2float(tt), LOG2E, abl));
        l += p0 + p1;
        acc = fmaf(p0, __low2float(sp), fmaf(p1, __high2float(sp), acc));
    }
    if (i < deg) {
        float sp0 = __half2float(__ushort_as_half(*(const unsigned short*)(splb + cbase[i])));
        float t0 = head_reduce(mish_aw(sp0 + rp, awc));
        float p = __builtin_amdgcn_exp2f(fmaf(t0, LOG2E, abl));
        l += p;
        acc = fmaf(p, sp0, acc);
    }
    out[(wave << 6) + lane] = (deg > 0) ? acc * __builtin_amdgcn_rcpf(l) : 0.f;
}

extern "C" void kernel_launch(void* const* d_in, const int* in_sizes, int n_in,
                              void* d_out, int out_size, void* d_ws, size_t ws_size,
                              hipStream_t stream) {
    const float* x  = (const float*)d_in[0];
    const float* Ws = (const float*)d_in[1];
    const float* bs = (const float*)d_in[2];
    const float* Wr = (const float*)d_in[3];
    const float* br = (const float*)d_in[4];
    const float* aw = (const float*)d_in[5];
    const float* ab = (const float*)d_in[6];
    const int* senders   = (const int*)d_in[7];
    const int* receivers = (const int*)d_in[8];
    float* out = (float*)d_out;

    // Workspace layout (~60 MB):
    char* wsp = (char*)d_ws;
    unsigned short* sph = (unsigned short*)wsp;  wsp += (size_t)N_NODES * EMBED * 2;  // 12.8 MB
    unsigned short* rph = (unsigned short*)wsp;  wsp += (size_t)N_NODES * EMBED * 2;  // 12.8 MB
    int* csr    = (int*)wsp;  wsp += (size_t)N_NODES * SLOTS * 4;    // 25.6 MB
    int* cursor = (int*)wsp;  wsp += (size_t)N_NODES * 4;            // 0.4 MB
    int* bkt    = (int*)wsp;  wsp += (size_t)NBKT * BKT_CAP * 4;     // 8.0 MB
    int* bktcnt = (int*)wsp;  wsp += 512 * 4;

    hipMemsetAsync(bktcnt, 0, NBKT * 4, stream);

    proj_bucketa_kernel<<<NBLK_PROJ + NTILE, 256, 0, stream>>>(
        x, Ws, bs, Wr, br, senders, receivers, sph, rph, bktcnt, bkt);

    bucketb_kernel<<<NBKT, 1024, 0, stream>>>(bktcnt, bkt, cursor, csr);

    int gather_blocks = (N_NODES * 64 + 255) / 256;
    fused_gather_kernel<<<gather_blocks, 256, 0, stream>>>(sph, rph, csr, cursor,
                                                           aw, ab, out);
}

// Round 15
// 128.260 us; speedup vs baseline: 1.5895x; 1.0405x over previous
//
#include <hip/hip_runtime.h>
#include <hip/hip_fp16.h>
#include <math.h>

#define N_NODES 100000
#define N_EDGES 1600000
#define EMBED 64
#define HEADS 4
#define HDIM 16

// Padded CSR: 64 slots per node (degree is Poisson(16); max over 100K nodes < 50)
#define SLOTS 64

// Two-phase bucket partition (no global returning atomics on the hot path):
#define BKT_SHIFT 8
#define BKT_NODES 256                         // receivers per bucket
#define NBKT 391                              // ceil(100000/256)
#define BKT_CAP 5120                          // mean 4096 + 16 sigma
#define TILE 4096                             // edges per bucketa-role block
#define NTILE 391                              // ceil(1600000/4096)
#define NGRP (N_EDGES / 4)                    // 400000 int4 groups

// proj role: 64 nodes/block, 16 nodes/wave -> FMA-bound (18 b128 vs 256 FMA-cyc per k4)
#define NODES_BLK 64
#define NBLK_PROJ 1563                        // ceil(100000/64)
#define SMEM_BYTES 52224                      // (2*64*68 + 64*68) * 4

#define LOG2E 1.44269504f

// Scalar-tail mish: tanh(softplus(z)) = 1 - 2/((1+e^z)^2 + 1); returns mish(z)*awc.
__device__ __forceinline__ float mish_aw(float z, float awc) {
    float ex  = __expf(fminf(z, 30.f));
    float u   = 1.f + ex;
    float den = fmaf(u, u, 1.f);
    float f   = fmaf(-2.f, __builtin_amdgcn_rcpf(den), 1.f);
    return z * awc * f;
}

// f32 DPP rotate-add: sum-reduce + broadcast across each 16-lane head group.
template<int CTRL>
__device__ __forceinline__ float ror_add(float t) {
    int x = __builtin_amdgcn_mov_dpp(__float_as_int(t), CTRL, 0xF, 0xF, true);
    return t + __int_as_float(x);
}
__device__ __forceinline__ float head_reduce(float t) {
    t = ror_add<0x121>(t);
    t = ror_add<0x122>(t);
    t = ror_add<0x124>(t);
    t = ror_add<0x128>(t);
    return t;
}

// Packed-f16 DPP rotate-add: reduces BOTH halves (two edges) at once.
template<int CTRL>
__device__ __forceinline__ __half2 hror_add(__half2 t) {
    int x = __builtin_amdgcn_mov_dpp(__builtin_bit_cast(int, t), CTRL, 0xF, 0xF, true);
    return __hadd2(t, __builtin_bit_cast(__half2, x));
}
__device__ __forceinline__ __half2 head_reduce_h2(__half2 t) {
    t = hror_add<0x121>(t);
    t = hror_add<0x122>(t);
    t = hror_add<0x124>(t);
    t = hror_add<0x128>(t);
    return t;
}

// ---------------- Fused kernel 1: proj (blocks 0..1562) + bucketa (1563..1953).
__global__ __launch_bounds__(256) void proj_bucketa_kernel(
        const float* __restrict__ x,
        const float* __restrict__ Ws, const float* __restrict__ bs,
        const float* __restrict__ Wr, const float* __restrict__ br,
        const int* __restrict__ senders, const int* __restrict__ receivers,
        unsigned short* __restrict__ sph, unsigned short* __restrict__ rph,
        int* __restrict__ bktcnt, int* __restrict__ bkt) {
    __shared__ __align__(16) char smem[SMEM_BYTES];
    int tid = threadIdx.x;
    if (blockIdx.x < NBLK_PROJ) {
        // ---- proj role: LDS-staged register-blocked GEMM, 16 nodes/wave.
        float* wsT = (float*)smem;            // [64*68]
        float* wrT = wsT + 64 * 68;           // [64*68]
        float* xsh = wrT + 64 * 68;           // [64*68]
        for (int i = tid; i < 4096; i += 256) {
            int k = i >> 6, o = i & 63;
            wsT[o * 68 + k] = Ws[i];
            wrT[o * 68 + k] = Wr[i];
        }
        int nb = blockIdx.x * NODES_BLK;
        // Stage 64 node rows of x (4096 floats = 1024 float4)
        for (int i = 0; i < 4; ++i) {
            int g = i * 256 + tid;
            int nl = g >> 4;                  // local node 0..63
            int k4 = g & 15;
            if (nb + nl < N_NODES) {
                float4 v = ((const float4*)(x + ((size_t)(nb + nl) << 6)))[k4];
                *(float4*)(xsh + nl * 68 + (k4 << 2)) = v;
            }
        }
        __syncthreads();
        int o = tid & 63;
        int w = tid >> 6;                     // wave id: nodes w*16..w*16+15
        float bsv = bs[o], brv = br[o];
        float accs[16], accr[16];
#pragma unroll
        for (int p = 0; p < 16; ++p) { accs[p] = bsv; accr[p] = brv; }
        const float4* ws4 = (const float4*)wsT + o * 17;
        const float4* wr4 = (const float4*)wrT + o * 17;
        const float4* xs4 = (const float4*)xsh + (w << 4) * 17;
#pragma unroll 4
        for (int k4 = 0; k4 < 16; ++k4) {
            float4 a = ws4[k4];
            float4 b = wr4[k4];
#pragma unroll
            for (int p = 0; p < 16; ++p) {
                float4 xv = xs4[p * 17 + k4];    // wave-uniform broadcast
                accs[p] += xv.x * a.x + xv.y * a.y + xv.z * a.z + xv.w * a.w;
                accr[p] += xv.x * b.x + xv.y * b.y + xv.z * b.z + xv.w * b.w;
            }
        }
        int node0 = nb + (w << 4);
#pragma unroll
        for (int p = 0; p < 16; ++p) {
            int node = node0 + p;
            if (node < N_NODES) {
                sph[(node << 6) + o] = __half_as_ushort(__float2half_rn(accs[p]));
                rph[(node << 6) + o] = __half_as_ushort(__float2half_rn(accr[p]));
            }
        }
    } else {
        // ---- bucketa role: LDS histogram -> one global atomic per (tile,bucket)
        // -> LDS-ranked scatter of packed ((r&255)<<17 | sender).
        int* hist = (int*)smem;               // [NBKT]
        int* base = hist + NBKT;
        int* cur  = base + NBKT;
        for (int i = tid; i < NBKT; i += 256) hist[i] = 0;
        __syncthreads();
        int g0 = (blockIdx.x - NBLK_PROJ) * (TILE / 4);
        int4 r[4], s[4];
        bool v[4];
#pragma unroll
        for (int t = 0; t < 4; ++t) {
            int g = g0 + t * 256 + tid;
            v[t] = (g < NGRP);
            if (v[t]) {
                r[t] = ((const int4*)receivers)[g];
                s[t] = ((const int4*)senders)[g];
                atomicAdd(&hist[r[t].x >> BKT_SHIFT], 1);
                atomicAdd(&hist[r[t].y >> BKT_SHIFT], 1);
                atomicAdd(&hist[r[t].z >> BKT_SHIFT], 1);
                atomicAdd(&hist[r[t].w >> BKT_SHIFT], 1);
            }
        }
        __syncthreads();
        for (int i = tid; i < NBKT; i += 256) {
            int h = hist[i];
            base[i] = (h > 0) ? atomicAdd(&bktcnt[i], h) : 0;
            cur[i] = 0;
        }
        __syncthreads();
#pragma unroll
        for (int t = 0; t < 4; ++t) {
            if (v[t]) {
                int b, rk, slot;
                b = r[t].x >> BKT_SHIFT; rk = atomicAdd(&cur[b], 1); slot = base[b] + rk;
                if (slot < BKT_CAP) bkt[b * BKT_CAP + slot] = ((r[t].x & (BKT_NODES - 1)) << 17) | s[t].x;
                b = r[t].y >> BKT_SHIFT; rk = atomicAdd(&cur[b], 1); slot = base[b] + rk;
                if (slot < BKT_CAP) bkt[b * BKT_CAP + slot] = ((r[t].y & (BKT_NODES - 1)) << 17) | s[t].y;
                b = r[t].z >> BKT_SHIFT; rk = atomicAdd(&cur[b], 1); slot = base[b] + rk;
                if (slot < BKT_CAP) bkt[b * BKT_CAP + slot] = ((r[t].z & (BKT_NODES - 1)) << 17) | s[t].z;
                b = r[t].w >> BKT_SHIFT; rk = atomicAdd(&cur[b], 1); slot = base[b] + rk;
                if (slot < BKT_CAP) bkt[b * BKT_CAP + slot] = ((r[t].w & (BKT_NODES - 1)) << 17) | s[t].w;
            }
        }
    }
}

// ---------------- Phase B: per-bucket CSR fill with LDS cursors.
// 391 blocks x 1024 threads. csr[r*64+slot] = sender*128 (byte offset);
// cursor[] (true degree) written at the end -> no cursor memset.
__global__ __launch_bounds__(1024) void bucketb_kernel(
        const int* __restrict__ bktcnt, const int* __restrict__ bkt,
        int* __restrict__ cursor, int* __restrict__ csr) {
    __shared__ int lcur[BKT_NODES];
    int tid = threadIdx.x;
    int b = blockIdx.x;
    if (tid < BKT_NODES) lcur[tid] = 0;
    __syncthreads();
    int cnt = bktcnt[b];
    if (cnt > BKT_CAP) cnt = BKT_CAP;
    const int* bb = bkt + b * BKT_CAP;
    for (int i = tid; i < cnt; i += 1024) {
        int vv = bb[i];
        int rl = vv >> 17;
        int sv = vv & 0x1FFFF;
        int slot = atomicAdd(&lcur[rl], 1);
        if (slot < SLOTS) csr[((((b << BKT_SHIFT) + rl)) << 6) + slot] = sv << 7;
    }
    __syncthreads();
    if (tid < BKT_NODES) {
        int node = (b << BKT_SHIFT) + tid;
        if (node < N_NODES) cursor[node] = lcur[tid];
    }
}

// ---------------- Fused per-node: logits + softmax + weighted gather.
// One wave per node; lane = output element (h*16+d). wave id forced scalar via
// readfirstlane so csr/cursor reads ride the SMEM pipe.
__global__ __launch_bounds__(256) void fused_gather_kernel(
                                    const unsigned short* __restrict__ sph,
                                    const unsigned short* __restrict__ rph,
                                    const int* __restrict__ csr,
                                    const int* __restrict__ cursor,
                                    const float* __restrict__ aw,
                                    const float* __restrict__ ab,
                                    float* __restrict__ out) {
    int wave = (blockIdx.x * blockDim.x + threadIdx.x) >> 6;   // grid covers exactly N_NODES
    wave = __builtin_amdgcn_readfirstlane(wave);               // provably wave-uniform
    int lane = threadIdx.x & 63;
    int deg = cursor[wave];                   // scalar load
    deg = (deg > SLOTS) ? SLOTS : deg;
    const int* cbase = csr + (wave << 6);     // uniform base -> s_load rows
    const char* splb = (const char*)sph + (lane << 1);   // csr holds byte offsets
    float rp  = __half2float(__ushort_as_half(rph[(wave << 6) + lane]));
    float awc = aw[lane & 15];
    float abl = ab[0] * LOG2E;                // exp2-domain offset for softmax
    __half2 k_pk    = __float2half2_rn(0.5f * LOG2E);
    __half2 rpk_pk  = __float2half2_rn(rp * 0.5f * LOG2E);
    __half2 aw_pk   = __float2half2_rn(awc);
    __half2 rpa_pk  = __float2half2_rn(rp * awc);
    __half2 ones    = __float2half2_rn(1.0f);
    __half2 neg2    = __float2half2_rn(-2.0f);
    float l = 0.f, acc = 0.f;
    int i = 0;
    for (; i + 8 <= deg; i += 8) {
        unsigned short su[8];
#pragma unroll
        for (int j = 0; j < 8; ++j) su[j] = *(const unsigned short*)(splb + cbase[i + j]);
#pragma unroll
        for (int j = 0; j < 4; ++j) {
            __half2 sp  = __halves2half2(__ushort_as_half(su[2 * j]),
                                         __ushort_as_half(su[2 * j + 1]));
            __half2 arg = __hfma2(sp, k_pk, rpk_pk);
            __half2 t2  = h2exp2(arg);
            __half2 w   = __hmul2(t2, t2);             // e^(sp+rp)
            __half2 u   = __hadd2(w, ones);
            __half2 den = __hfma2(u, u, ones);
            __half2 r   = h2rcp(den);
            __half2 f   = __hfma2(neg2, r, ones);
            __half2 za  = __hfma2(sp, aw_pk, rpa_pk);
            __half2 tt  = head_reduce_h2(__hmul2(za, f));
            float p0 = __builtin_amdgcn_exp2f(fmaf(__low2float(tt),  LOG2E, abl));
            float p1 = __builtin_amdgcn_exp2f(fmaf(__high2float(tt), LOG2E, abl));
            l += p0 + p1;
            acc = fmaf(p0, __low2float(sp), fmaf(p1, __high2float(sp), acc));
        }
    }
    for (; i + 2 <= deg; i += 2) {
        __half2 sp  = __halves2half2(__ushort_as_half(*(const unsigned short*)(splb + cbase[i])),
                                     __ushort_as_half(*(const unsigned short*)(splb + cbase[i + 1])));
        __half2 arg = __hfma2(sp, k_pk, rpk_pk);
        __half2 t2  = h2exp2(arg);
        __half2 w   = __hmul2(t2, t2);
        __half2 u   = __hadd2(w, ones);
        __half2 den = __hfma2(u, u, ones);
        __half2 r   = h2rcp(den);
        __half2 f   = __hfma2(neg2, r, ones);
        __half2 za  = __hfma2(sp, aw_pk, rpa_pk);
        __half2 tt  = head_reduce_h2(__hmul2(za, f));
        float p0 = __builtin_amdgcn_exp2f(fmaf(__low2float(tt),  LOG2E, abl));
        float p1 = __builtin_amdgcn_exp2f(fmaf(__high2float(tt), LOG2E, abl));
        l += p0 + p1;
        acc = fmaf(p0, __low2float(sp), fmaf(p1, __high2float(sp), acc));
    }
    if (i < deg) {
        float sp0 = __half2float(__ushort_as_half(*(const unsigned short*)(splb + cbase[i])));
        float t0 = head_reduce(mish_aw(sp0 + rp, awc));
        float p = __builtin_amdgcn_exp2f(fmaf(t0, LOG2E, abl));
        l += p;
        acc = fmaf(p, sp0, acc);
    }
    out[(wave << 6) + lane] = (deg > 0) ? acc * __builtin_amdgcn_rcpf(l) : 0.f;
}

extern "C" void kernel_launch(void* const* d_in, const int* in_sizes, int n_in,
                              void* d_out, int out_size, void* d_ws, size_t ws_size,
                              hipStream_t stream) {
    const float* x  = (const float*)d_in[0];
    const float* Ws = (const float*)d_in[1];
    const float* bs = (const float*)d_in[2];
    const float* Wr = (const float*)d_in[3];
    const float* br = (const float*)d_in[4];
    const float* aw = (const float*)d_in[5];
    const float* ab = (const float*)d_in[6];
    const int* senders   = (const int*)d_in[7];
    const int* receivers = (const int*)d_in[8];
    float* out = (float*)d_out;

    // Workspace layout (~60 MB):
    char* wsp = (char*)d_ws;
    unsigned short* sph = (unsigned short*)wsp;  wsp += (size_t)N_NODES * EMBED * 2;  // 12.8 MB
    unsigned short* rph = (unsigned short*)wsp;  wsp += (size_t)N_NODES * EMBED * 2;  // 12.8 MB
    int* csr    = (int*)wsp;  wsp += (size_t)N_NODES * SLOTS * 4;    // 25.6 MB
    int* cursor = (int*)wsp;  wsp += (size_t)N_NODES * 4;            // 0.4 MB
    int* bkt    = (int*)wsp;  wsp += (size_t)NBKT * BKT_CAP * 4;     // 8.0 MB
    int* bktcnt = (int*)wsp;  wsp += 512 * 4;

    hipMemsetAsync(bktcnt, 0, NBKT * 4, stream);

    proj_bucketa_kernel<<<NBLK_PROJ + NTILE, 256, 0, stream>>>(
        x, Ws, bs, Wr, br, senders, receivers, sph, rph, bktcnt, bkt);

    bucketb_kernel<<<NBKT, 1024, 0, stream>>>(bktcnt, bkt, cursor, csr);

    int gather_blocks = (N_NODES * 64 + 255) / 256;
    fused_gather_kernel<<<gather_blocks, 256, 0, stream>>>(sph, rph, csr, cursor,
                                                           aw, ab, out);
}